// Round 1
// baseline (704.323 us; speedup 1.0000x reference)
//
#include <hip/hip_runtime.h>

#define BB   32
#define TT   1024
#define VV   1024
#define LMAXC 128
#define SS   257        // 2*LMAX+1 extended states
#define SP   260        // padded row stride (16B aligned)
#define NEGF (-1e30f)

// ---------------------------------------------------------------------------
// Kernel A: one block per (b,t) frame row.
//  - loads the 1024-float logit row (float4, coalesced), stages in LDS
//  - block-reduces max and sum(exp(x-max)) -> LSE
//  - atomicAdd(LSE) into per-batch sum (only t < hlen; others exit early)
//  - gathers the 257 extended-label raw logits from LDS -> lp_raw[b,t,:]
// ---------------------------------------------------------------------------
__global__ __launch_bounds__(256) void ctc_row_kernel(
    const float* __restrict__ ys_hat, const int* __restrict__ ys_pad,
    const int* __restrict__ hlens, float* __restrict__ lp_raw,
    float* __restrict__ ssum)
{
    const int row = blockIdx.x;          // 0 .. B*T-1
    const int b = row >> 10;             // T = 1024
    const int t = row & (TT - 1);
    if (t >= hlens[b]) return;           // frame beyond hlen: contributes nothing

    __shared__ float srow[VV];
    __shared__ float redmax[4];
    __shared__ float redsum[4];

    const int tid  = threadIdx.x;
    const int lane = tid & 63;
    const int wid  = tid >> 6;

    const float4 v = ((const float4*)(ys_hat + (size_t)row * VV))[tid];
    ((float4*)srow)[tid] = v;

    // block max
    float mx = fmaxf(fmaxf(v.x, v.y), fmaxf(v.z, v.w));
    #pragma unroll
    for (int off = 32; off > 0; off >>= 1)
        mx = fmaxf(mx, __shfl_xor(mx, off));
    if (lane == 0) redmax[wid] = mx;
    __syncthreads();
    mx = fmaxf(fmaxf(redmax[0], redmax[1]), fmaxf(redmax[2], redmax[3]));

    // block sum(exp(x - mx))
    float sm = __expf(v.x - mx) + __expf(v.y - mx) +
               __expf(v.z - mx) + __expf(v.w - mx);
    #pragma unroll
    for (int off = 32; off > 0; off >>= 1)
        sm += __shfl_xor(sm, off);
    if (lane == 0) redsum[wid] = sm;
    __syncthreads();
    sm = redsum[0] + redsum[1] + redsum[2] + redsum[3];

    if (tid == 0)
        atomicAdd(&ssum[b], mx + __logf(sm));

    // gather extended-label raw logits (srow visible: synced above)
    float* lpo = lp_raw + (size_t)row * SP;
    const int ext = (tid & 1) ? ys_pad[b * LMAXC + (tid >> 1)] : 0;  // blank = 0
    lpo[tid] = srow[ext];
    if (tid == 0) lpo[256] = srow[0];    // s = 256 is even -> blank
}

// ---------------------------------------------------------------------------
// Kernel B: one block per batch element; thread s owns extended state s.
// DP on RAW gathered logits (the -LSE[t] per step is uniform across states
// and factored out: loss = ssum[b] - logaddexp(a1_raw, a2_raw)).
// Freeze at t >= hlen is equivalent to stopping the loop at hlen-1.
// ---------------------------------------------------------------------------
__global__ __launch_bounds__(320) void ctc_dp_kernel(
    const float* __restrict__ lp_raw, const int* __restrict__ ys_pad,
    const int* __restrict__ hlens, const int* __restrict__ ys_lens,
    const float* __restrict__ ssum, float* __restrict__ out)
{
    const int b = blockIdx.x;
    const int s = threadIdx.x;
    const bool active = (s < SS);

    __shared__ float abuf[2][SS + 3];

    const int hl = hlens[b];
    const float* lp = lp_raw + (size_t)b * TT * SP;

    // skip transition allowed iff s odd, s>=3, label != label two back
    bool skip = false;
    if (active && (s & 1) && s >= 3)
        skip = (ys_pad[b * LMAXC + (s >> 1)] !=
                ys_pad[b * LMAXC + (s >> 1) - 1]);

    // t = 0 init: only s=0 (blank) and s=1 (first label) reachable
    float a = NEGF;
    if (active) {
        a = (s <= 1) ? lp[s] : NEGF;
        abuf[0][s] = a;
    }
    __syncthreads();

    int cur = 0;
    float lp_cur = active ? lp[SP + s] : 0.0f;   // t = 1 (hl >= 512 always)
    for (int t = 1; t < hl; ++t) {
        const int tn = (t + 1 < hl) ? (t + 1) : t;
        const float lp_nxt = active ? lp[(size_t)tn * SP + s] : 0.0f; // prefetch
        if (active) {
            const float a1 = (s >= 1) ? abuf[cur][s - 1] : NEGF;
            const float a2 = skip ? abuf[cur][s - 2] : NEGF;
            const float m  = fmaxf(a, fmaxf(a1, a2));
            const float sum = __expf(a - m) + __expf(a1 - m) + __expf(a2 - m);
            a = m + __logf(sum) + lp_cur;
            abuf[cur ^ 1][s] = a;
        }
        __syncthreads();
        cur ^= 1;
        lp_cur = lp_nxt;
    }

    if (s == 0) {
        const int L  = ys_lens[b];
        const float a1 = abuf[cur][2 * L];
        const float a2 = abuf[cur][2 * L - 1];
        const float m  = fmaxf(a1, a2);
        const float lse = m + __logf(__expf(a1 - m) + __expf(a2 - m));
        atomicAdd(out, (ssum[b] - lse) * (1.0f / (float)BB));
    }
}

extern "C" void kernel_launch(void* const* d_in, const int* in_sizes, int n_in,
                              void* d_out, int out_size, void* d_ws, size_t ws_size,
                              hipStream_t stream) {
    const float* ys_hat  = (const float*)d_in[0];
    const int*   ys_pad  = (const int*)d_in[1];
    const int*   hlens   = (const int*)d_in[2];
    const int*   ys_lens = (const int*)d_in[3];
    float* out = (float*)d_out;

    float* ssum   = (float*)d_ws;                       // 32 floats
    float* lp_raw = (float*)((char*)d_ws + 256);        // [B, T, SP] floats

    hipMemsetAsync(d_out, 0, sizeof(float), stream);
    hipMemsetAsync(d_ws, 0, 256, stream);

    ctc_row_kernel<<<BB * TT, 256, 0, stream>>>(ys_hat, ys_pad, hlens, lp_raw, ssum);
    ctc_dp_kernel<<<BB, 320, 0, stream>>>(lp_raw, ys_pad, hlens, ys_lens, ssum, out);
}

// Round 2
// 443.191 us; speedup vs baseline: 1.5892x; 1.5892x over previous
//
#include <hip/hip_runtime.h>

#define BB    32
#define TT    1024
#define VV    1024
#define LMAXC 128
#define SS    257        // 2*LMAX+1 extended states
#define SP    260        // padded row stride; slot 257 holds the row LSE
#define NEGF  (-1e30f)
#define PF    8          // register prefetch depth (and inner unroll)

// ---------------------------------------------------------------------------
// Kernel A: one block per (b,t) frame row.
//  - loads the 1024-float logit row (float4, coalesced), stages in LDS
//  - block-reduces max and sum(exp(x-max)) -> LSE, stored at lpo[257]
//    (NO global atomics -- round-1's ssum atomicAdd serialized ~385us)
//  - gathers the 257 extended-label raw logits from LDS -> lp_raw[b,t,:]
// ---------------------------------------------------------------------------
__global__ __launch_bounds__(256) void ctc_row_kernel(
    const float* __restrict__ ys_hat, const int* __restrict__ ys_pad,
    const int* __restrict__ hlens, float* __restrict__ lp_raw)
{
    const int row = blockIdx.x;          // 0 .. B*T-1
    const int b = row >> 10;             // T = 1024
    const int t = row & (TT - 1);
    if (t >= hlens[b]) return;           // frame beyond hlen: contributes nothing

    __shared__ float srow[VV];
    __shared__ float redmax[4];
    __shared__ float redsum[4];

    const int tid  = threadIdx.x;
    const int lane = tid & 63;
    const int wid  = tid >> 6;

    const float4 v = ((const float4*)(ys_hat + (size_t)row * VV))[tid];
    ((float4*)srow)[tid] = v;

    float mx = fmaxf(fmaxf(v.x, v.y), fmaxf(v.z, v.w));
    #pragma unroll
    for (int off = 32; off > 0; off >>= 1)
        mx = fmaxf(mx, __shfl_xor(mx, off));
    if (lane == 0) redmax[wid] = mx;
    __syncthreads();
    mx = fmaxf(fmaxf(redmax[0], redmax[1]), fmaxf(redmax[2], redmax[3]));

    float sm = __expf(v.x - mx) + __expf(v.y - mx) +
               __expf(v.z - mx) + __expf(v.w - mx);
    #pragma unroll
    for (int off = 32; off > 0; off >>= 1)
        sm += __shfl_xor(sm, off);
    if (lane == 0) redsum[wid] = sm;
    __syncthreads();
    sm = redsum[0] + redsum[1] + redsum[2] + redsum[3];

    // gather extended-label raw logits (srow visible: synced above)
    float* lpo = lp_raw + (size_t)row * SP;
    const int ext = (tid & 1) ? ys_pad[b * LMAXC + (tid >> 1)] : 0;  // blank = 0
    lpo[tid] = srow[ext];
    if (tid == 0) {
        lpo[256] = srow[0];              // s = 256 is even -> blank
        lpo[257] = mx + __logf(sm);      // row LSE (factored out of the DP)
    }
}

// ---------------------------------------------------------------------------
// Kernel B: one block per batch element; thread s owns extended state s.
// DP on RAW gathered logits; per-step -LSE[t] is uniform across states and
// factored out: loss = sum_t LSE[t] - logaddexp(a1_raw, a2_raw).
// lp loads use an 8-deep register prefetch ring (chunked, fully unrolled) so
// each step's lp value was issued 8 steps earlier -- hides L2/HBM latency.
// ---------------------------------------------------------------------------
__global__ __launch_bounds__(320) void ctc_dp_kernel(
    const float* __restrict__ lp_raw, const int* __restrict__ ys_pad,
    const int* __restrict__ hlens, const int* __restrict__ ys_lens,
    float* __restrict__ out)
{
    const int b = blockIdx.x;
    const int s = threadIdx.x;
    const bool active = (s < SS);
    const int sc = active ? s : 0;       // safe column for inactive threads

    __shared__ float abuf[2][SS + 3];
    __shared__ float lsred[5];
    __shared__ float ssum_sh;

    const int hl = hlens[b];
    const float* lp = lp_raw + (size_t)b * TT * SP;

    // per-batch sum of row LSEs (replaces round-1's contended atomics)
    float ls = 0.0f;
    for (int t = s; t < hl; t += 320) ls += lp[(size_t)t * SP + 257];
    #pragma unroll
    for (int off = 32; off > 0; off >>= 1) ls += __shfl_xor(ls, off);
    if ((s & 63) == 0) lsred[s >> 6] = ls;

    // skip transition allowed iff s odd, s>=3, label != label two back
    bool skip = false;
    if (active && (s & 1) && s >= 3)
        skip = (ys_pad[b * LMAXC + (s >> 1)] !=
                ys_pad[b * LMAXC + (s >> 1) - 1]);

    // t = 0 init: only s=0 (blank) and s=1 (first label) reachable
    float a = NEGF;
    if (active) {
        a = (s <= 1) ? lp[s] : NEGF;
        abuf[0][s] = a;
    }
    __syncthreads();
    if (s == 0) ssum_sh = lsred[0] + lsred[1] + lsred[2] + lsred[3] + lsred[4];

    // prime the prefetch ring: pre[j] = lp for step t = 1+j  (hl >= 512)
    float pre[PF];
    #pragma unroll
    for (int j = 0; j < PF; ++j) pre[j] = lp[(size_t)(1 + j) * SP + sc];

    int cur = 0;
    for (int t0 = 1; t0 < hl; t0 += PF) {
        #pragma unroll
        for (int j = 0; j < PF; ++j) {
            const int t = t0 + j;
            const float lp_cur = pre[j];
            int tpre = t + PF; if (tpre > TT - 1) tpre = TT - 1;
            pre[j] = lp[(size_t)tpre * SP + sc];   // issue 8 steps ahead
            if (t < hl) {                           // block-uniform predicate
                if (active) {
                    const float a1 = (s >= 1) ? abuf[cur][s - 1] : NEGF;
                    const float a2 = skip ? abuf[cur][s - 2] : NEGF;
                    const float m  = fmaxf(a, fmaxf(a1, a2));
                    a = m + __logf(__expf(a - m) + __expf(a1 - m) +
                                   __expf(a2 - m)) + lp_cur;
                    abuf[cur ^ 1][s] = a;
                }
                __syncthreads();
                cur ^= 1;
            }
        }
    }

    if (s == 0) {
        const int L  = ys_lens[b];
        const float a1 = abuf[cur][2 * L];
        const float a2 = abuf[cur][2 * L - 1];
        const float m  = fmaxf(a1, a2);
        const float lse = m + __logf(__expf(a1 - m) + __expf(a2 - m));
        atomicAdd(out, (ssum_sh - lse) * (1.0f / (float)BB));
    }
}

extern "C" void kernel_launch(void* const* d_in, const int* in_sizes, int n_in,
                              void* d_out, int out_size, void* d_ws, size_t ws_size,
                              hipStream_t stream) {
    const float* ys_hat  = (const float*)d_in[0];
    const int*   ys_pad  = (const int*)d_in[1];
    const int*   hlens   = (const int*)d_in[2];
    const int*   ys_lens = (const int*)d_in[3];
    float* out = (float*)d_out;

    float* lp_raw = (float*)d_ws;        // [B, T, SP] floats (~34 MB)

    hipMemsetAsync(d_out, 0, sizeof(float), stream);

    ctc_row_kernel<<<BB * TT, 256, 0, stream>>>(ys_hat, ys_pad, hlens, lp_raw);
    ctc_dp_kernel<<<BB, 320, 0, stream>>>(lp_raw, ys_pad, hlens, ys_lens, out);
}